// Round 3
// baseline (877.509 us; speedup 1.0000x reference)
//
#include <hip/hip_runtime.h>
#include <math.h>

constexpr int S = 200;    // base dim
constexpr int NBATCH = 16;
constexpr int SS = S * S;         // 40000
constexpr int FLAT = S * NBATCH;  // 3200
constexpr int SLICE = S * FLAT;   // 640000 complex per GEMM output

// ---------------- threefry2x32 (JAX-compatible, 20 rounds) ----------------
struct TFOut { unsigned a, b; };

__host__ __device__ constexpr TFOut tf2x32(unsigned k0, unsigned k1,
                                           unsigned x0, unsigned x1) {
  unsigned ks2 = k0 ^ k1 ^ 0x1BD11BDAu;
  unsigned ks[3] = {k0, k1, ks2};
  const int R0[4] = {13, 15, 26, 6};
  const int R1[4] = {17, 29, 16, 24};
  x0 += ks[0]; x1 += ks[1];
  for (int i = 0; i < 5; ++i) {
    const int* R = (i & 1) ? R1 : R0;
    for (int j = 0; j < 4; ++j) {
      x0 += x1;
      x1 = (x1 << R[j]) | (x1 >> (32 - R[j]));
      x1 ^= x0;
    }
    x0 += ks[(i + 1) % 3];
    x1 += ks[(i + 2) % 3] + (unsigned)(i + 1);
  }
  return {x0, x1};
}

constexpr TFOut KEY1 = tf2x32(0u, 42u, 0u, 0u);  // phase key
constexpr TFOut KEY2 = tf2x32(0u, 42u, 0u, 1u);  // intensity key

// ---------------- gumbel helpers ----------------
__device__ inline float bits_to_u(unsigned bits) {
  float f = __uint_as_float((bits >> 9) | 0x3f800000u) - 1.0f;
  f = f + 1e-10f;
  return fmaxf(1e-10f, f);
}

// exact path (baseline-identical): each log correctly rounded via double
__device__ inline float u_to_g_exact(float u) {
  float l1 = (float)log((double)u);
  float l2 = (float)log((double)(-l1));
  return -l2;
}

// fast path: ocml logf (<=1 ulp); |g_fast - g_exact| <~ 2.3e-6
__device__ inline float u_to_g_fast(float u) {
  float l1 = logf(u);
  float l2 = logf(-l1);
  return -l2;
}

__device__ inline unsigned ordf(float f) {
  unsigned u = __float_as_uint(f);
  return (u & 0x80000000u) ? ~u : (u | 0x80000000u);
}
__device__ inline float unordf(unsigned u) {
  return (u & 0x80000000u) ? __uint_as_float(u ^ 0x80000000u)
                           : __uint_as_float(~u);
}
__device__ inline unsigned long long packcand(float val, int p) {
  return ((unsigned long long)ordf(val) << 32) | (unsigned)(255 - p);
}

__global__ __launch_bounds__(256) void gumbel_kernel(
    const float* __restrict__ voltage, const float* __restrict__ phase_func,
    const float* __restrict__ intensity_func, float2* __restrict__ PT) {
  const int q = blockIdx.x;
  const int p = threadIdx.x;
  const unsigned idx = (unsigned)q * 256u + (unsigned)p;
  const float v = voltage[(size_t)q * 256 + p];
  TFOut r1 = tf2x32(KEY1.a, KEY1.b, 0u, idx);
  TFOut r2 = tf2x32(KEY2.a, KEY2.b, 0u, idx);
  const float u1 = bits_to_u(r1.a ^ r1.b);
  const float u2 = bits_to_u(r2.a ^ r2.b);
  const float c1a = (v + u_to_g_fast(u1)) * 0.1f;
  const float c2a = (v + u_to_g_fast(u2)) * 0.1f;

  __shared__ unsigned smax[2];
  __shared__ unsigned long long red[2];
  if (p < 2) { smax[p] = 0u; red[p] = 0ull; }
  __syncthreads();
  atomicMax(&smax[0], ordf(c1a));
  atomicMax(&smax[1], ordf(c2a));
  __syncthreads();
  const float eps = 1e-5f;
  const float m1 = unordf(smax[0]) - eps;
  const float m2 = unordf(smax[1]) - eps;
  if (c1a >= m1) {
    float c1 = (v + u_to_g_exact(u1)) / 10.0f;
    atomicMax(&red[0], packcand(c1, p));
  }
  if (c2a >= m2) {
    float c2 = (v + u_to_g_exact(u2)) / 10.0f;
    atomicMax(&red[1], packcand(c2, p));
  }
  __syncthreads();
  if (p == 0) {
    int i1 = 255 - (int)(red[0] & 0xFFFFFFFFull);
    int i2 = 255 - (int)(red[1] & 0xFFFFFFFFull);
    float phi = phase_func[i1];
    float amp = intensity_func[i2] * 6.0f;
    PT[q] = make_float2(amp * cosf(phi), amp * sinf(phi));
  }
}

// ---------------- DFT tables + packing ----------------
__global__ __launch_bounds__(256) void build_tables(
    const float* __restrict__ h_real, const float* __restrict__ h_imag,
    float2* __restrict__ F, float2* __restrict__ G, float2* __restrict__ Hc) {
  int idx = blockIdx.x * 256 + threadIdx.x;
  if (idx >= SS) return;
  int j = idx / S;
  int k = idx - j * S;
  int m = (j * k) % S;
  double ang = -2.0 * 3.14159265358979323846 * (double)m / (double)S;
  double c = cos(ang), s = sin(ang);
  F[idx] = make_float2((float)c, (float)s);
  G[idx] = make_float2((float)(c * 0.005), (float)(-s * 0.005));  // conj/200
  Hc[idx] = make_float2(h_real[idx], h_imag[idx]);
}

__global__ __launch_bounds__(256) void pack_waves(
    const float* __restrict__ re, const float* __restrict__ im,
    float2* __restrict__ W) {
  int idx = blockIdx.x * 256 + threadIdx.x;  // 2500*256 = 640000 exact
  W[idx] = make_float2(re[idx], im[idx]);
}

// ---------------- K-split flat complex GEMM ----------------
// APERM=false: C(200 x 3200) = A(200x200) @ B'(200x3200),
//   B'[k][b*200+n] = B[b*40000 + k*200 + n] (optional .* Hm[k*200+n])
// APERM=true : C(3200 x 200) = A'(3200x200) @ B(200x200),
//   A'[b*200+i][k] = A[i*3200 + b*200 + k]
// blockIdx.z = k-split index; each writes its own SLICE partial (no atomics).
template <bool APERM, bool MASK>
__global__ __launch_bounds__(256) void cgemm_ks(
    const float2* __restrict__ A, const float2* __restrict__ B,
    const float2* __restrict__ Hm, float2* __restrict__ Cp,
    int M, int N, int K, int KSlice) {
  __shared__ __align__(16) float2 As[16][64];  // [k][m]
  __shared__ __align__(16) float2 Bs[16][64];  // [k][n]
  const int tid = threadIdx.x;
  const int rowBase = blockIdx.x * 64;
  const int colBase = blockIdx.y * 64;
  const int Kbeg = blockIdx.z * KSlice;
  const int Kend = min(Kbeg + KSlice, K);

  const int a_m = tid >> 2;          // 0..63
  const int a_k4 = (tid & 3) * 4;    // 0,4,8,12
  const int b_k = tid >> 4;          // 0..15
  const int b_n4 = (tid & 15) * 4;   // 0..60
  const int tx4 = (tid & 15) * 4;
  const int ty4 = (tid >> 4) * 4;

  // A row base
  long arow;
  bool arow_ok;
  {
    int gm = rowBase + a_m;
    if (APERM) {
      int b = gm / S, i = gm - b * S;  // gm < 3200 always (grid exact)
      arow = (long)i * FLAT + (long)b * S;
      arow_ok = true;
    } else {
      arow_ok = (gm < M);
      arow = (long)gm * S;
    }
  }
  // B column base
  long bcol;
  int nmod = 0;
  bool bcol_ok;
  {
    int gn = colBase + b_n4;
    if (APERM) {
      bcol = gn;               // plain 200-wide B
      bcol_ok = (gn < N);
    } else {
      int b = gn / S;
      nmod = gn - b * S;       // 4-aligned, never straddles (200 % 4 == 0)
      bcol = (long)b * SS + nmod;
      bcol_ok = true;
    }
  }

  float2 acc[4][4];
#pragma unroll
  for (int i = 0; i < 4; ++i)
#pragma unroll
    for (int j = 0; j < 4; ++j) acc[i][j] = make_float2(0.f, 0.f);

  for (int k0 = Kbeg; k0 < Kend; k0 += 16) {
    const int gka = k0 + a_k4;
    float4 av0 = {0, 0, 0, 0}, av1 = {0, 0, 0, 0};
    if (arow_ok) {
      if (gka < Kend) av0 = *(const float4*)&A[arow + gka];
      if (gka + 2 < Kend) av1 = *(const float4*)&A[arow + gka + 2];
    }
    const int gkb = k0 + b_k;
    float4 bv0 = {0, 0, 0, 0}, bv1 = {0, 0, 0, 0};
    if (bcol_ok && gkb < Kend) {
      const float2* bp = &B[bcol + (long)gkb * S];
      bv0 = *(const float4*)bp;
      bv1 = *(const float4*)(bp + 2);
      if (MASK) {
        const float2* hp = &Hm[(long)gkb * S + nmod];
        float4 h0 = *(const float4*)hp;
        float4 h1 = *(const float4*)(hp + 2);
        bv0 = make_float4(bv0.x * h0.x - bv0.y * h0.y, bv0.x * h0.y + bv0.y * h0.x,
                          bv0.z * h0.z - bv0.w * h0.w, bv0.z * h0.w + bv0.w * h0.z);
        bv1 = make_float4(bv1.x * h1.x - bv1.y * h1.y, bv1.x * h1.y + bv1.y * h1.x,
                          bv1.z * h1.z - bv1.w * h1.w, bv1.z * h1.w + bv1.w * h1.z);
      }
    }
    __syncthreads();  // prior compute done before LDS overwrite
    As[a_k4 + 0][a_m] = make_float2(av0.x, av0.y);
    As[a_k4 + 1][a_m] = make_float2(av0.z, av0.w);
    As[a_k4 + 2][a_m] = make_float2(av1.x, av1.y);
    As[a_k4 + 3][a_m] = make_float2(av1.z, av1.w);
    *(float4*)&Bs[b_k][b_n4] = bv0;
    *(float4*)&Bs[b_k][b_n4 + 2] = bv1;
    __syncthreads();
#pragma unroll
    for (int kk = 0; kk < 16; ++kk) {
      float4 aA = *(const float4*)&As[kk][ty4];
      float4 aB = *(const float4*)&As[kk][ty4 + 2];
      float4 bA = *(const float4*)&Bs[kk][tx4];
      float4 bB = *(const float4*)&Bs[kk][tx4 + 2];
      float2 a[4] = {{aA.x, aA.y}, {aA.z, aA.w}, {aB.x, aB.y}, {aB.z, aB.w}};
      float2 b[4] = {{bA.x, bA.y}, {bA.z, bA.w}, {bB.x, bB.y}, {bB.z, bB.w}};
#pragma unroll
      for (int i = 0; i < 4; ++i)
#pragma unroll
        for (int j = 0; j < 4; ++j) {
          acc[i][j].x = fmaf(a[i].x, b[j].x, fmaf(-a[i].y, b[j].y, acc[i][j].x));
          acc[i][j].y = fmaf(a[i].x, b[j].y, fmaf(a[i].y, b[j].x, acc[i][j].y));
        }
    }
  }
  float2* Co = Cp + (long)blockIdx.z * SLICE;
#pragma unroll
  for (int rr = 0; rr < 4; ++rr) {
    const int r = rowBase + ty4 + rr;
    const int cb = colBase + tx4;
    if (r < M && cb < N) {
      *(float4*)&Co[(long)r * N + cb] = make_float4(acc[rr][0].x, acc[rr][0].y,
                                                    acc[rr][1].x, acc[rr][1].y);
      *(float4*)&Co[(long)r * N + cb + 2] = make_float4(acc[rr][2].x, acc[rr][2].y,
                                                        acc[rr][3].x, acc[rr][3].y);
    }
  }
}

// ---------------- K-split reduction ----------------
__global__ __launch_bounds__(256) void reduce4(
    const float4* __restrict__ P, float4* __restrict__ D) {
  int i = blockIdx.x * 256 + threadIdx.x;  // 320000 float4 = 640000 complex
  if (i >= SLICE / 2) return;
  float4 a = P[i], b = P[i + SLICE / 2], c = P[i + SLICE], d = P[i + 3 * SLICE / 2];
  D[i] = make_float4(a.x + b.x + c.x + d.x, a.y + b.y + c.y + d.y,
                     a.z + b.z + c.z + d.z, a.w + b.w + c.w + d.w);
}

// last reduce: also multiply by per-pixel phase-trig PT
__global__ __launch_bounds__(256) void reduce4_pt(
    const float2* __restrict__ P, const float2* __restrict__ PT,
    float2* __restrict__ D) {
  int i = blockIdx.x * 256 + threadIdx.x;  // 640000 complex
  if (i >= SLICE) return;
  float2 a = P[i], b = P[i + SLICE], c = P[i + 2 * SLICE], d = P[i + 3 * SLICE];
  float sx = a.x + b.x + c.x + d.x;
  float sy = a.y + b.y + c.y + d.y;
  float2 pt = PT[i % SS];  // rows are b*200+i, cols j -> pixel = i%40000
  D[i] = make_float2(sx * pt.x - sy * pt.y, sx * pt.y + sy * pt.x);
}

// ---------------- 10x pixel expansion (pure replicate) ----------------
__global__ __launch_bounds__(256) void expand_kernel(
    const float2* __restrict__ Xc, float4* __restrict__ out) {
  unsigned q = blockIdx.x * 256u + threadIdx.x;  // < 32,000,000 exact
  unsigned p0 = q * 2u;
  unsigned b = p0 / 4000000u;
  unsigned rem = p0 - b * 4000000u;
  unsigned r = rem / 2000u;
  unsigned c0 = rem - r * 2000u;
  unsigned i = r / 10u;
  unsigned dr = r - i * 10u;
  float4 o = {0.f, 0.f, 0.f, 0.f};
  if (dr - 1u <= 7u) {  // dr in [1,8]
    unsigned j = c0 / 10u;
    unsigned dc = c0 - j * 10u;  // even: 0,2,4,6,8
    float2 xv = Xc[b * 40000u + i * 200u + j];
    if (dc != 0u) { o.x = xv.x; o.y = xv.y; }
    if (dc != 8u) { o.z = xv.x; o.w = xv.y; }
  }
  out[q] = o;
}

// ---------------- launch ----------------
extern "C" void kernel_launch(void* const* d_in, const int* in_sizes, int n_in,
                              void* d_out, int out_size, void* d_ws, size_t ws_size,
                              hipStream_t stream) {
  const float* waves_real = (const float*)d_in[0];
  const float* waves_imag = (const float*)d_in[1];
  const float* h_real = (const float*)d_in[2];
  const float* h_imag = (const float*)d_in[3];
  const float* voltage = (const float*)d_in[4];
  const float* phase_func = (const float*)d_in[5];
  const float* intensity_func = (const float*)d_in[6];

  float2* F    = (float2*)d_ws;       // 40000
  float2* G    = F + SS;              // 40000
  float2* Hc   = G + SS;              // 40000
  float2* PT   = Hc + SS;             // 40000
  float2* Wc   = PT + SS;             // 640000
  float2* T1   = Wc + SLICE;          // 640000 (200 x 3200)
  float2* T2   = T1 + SLICE;          // 640000 (rows b*200+k, cols n)
  float2* T4   = T2 + SLICE;          // 640000 (200 x 3200)
  float2* Xc   = T4 + SLICE;          // 640000 (rows b*200+i, cols j)
  float2* Part = Xc + SLICE;          // 4 x 640000 partials (~47 MB total ws)

  build_tables<<<157, 256, 0, stream>>>(h_real, h_imag, F, G, Hc);
  pack_waves<<<2500, 256, 0, stream>>>(waves_real, waves_imag, Wc);
  gumbel_kernel<<<40000, 256, 0, stream>>>(voltage, phase_func, intensity_func, PT);

  dim3 gB(4, 50, 4);   // rows(200) x cols(3200) x ksplit
  dim3 gA(50, 4, 4);   // rows(3200) x cols(200) x ksplit

  // T1 = F @ W'            (fft axis 0, batch-flattened cols)
  cgemm_ks<false, false><<<gB, 256, 0, stream>>>(F, Wc, nullptr, Part, S, FLAT, S, 50);
  reduce4<<<1250, 256, 0, stream>>>((const float4*)Part, (float4*)T1);
  // T2 = T1' @ F           (fft axis 1, batch-permuted rows)
  cgemm_ks<true, false><<<gA, 256, 0, stream>>>(T1, F, nullptr, Part, FLAT, S, S, 50);
  reduce4<<<1250, 256, 0, stream>>>((const float4*)Part, (float4*)T2);
  // T4 = G @ (T2' .* h)    (ifft axis 0, h fused)
  cgemm_ks<false, true><<<gB, 256, 0, stream>>>(G, T2, Hc, Part, S, FLAT, S, 50);
  reduce4<<<1250, 256, 0, stream>>>((const float4*)Part, (float4*)T4);
  // Xc = (T4' @ G) .* PT   (ifft axis 1 + phase-trig fused into reduce)
  cgemm_ks<true, false><<<gA, 256, 0, stream>>>(T4, G, nullptr, Part, FLAT, S, S, 50);
  reduce4_pt<<<2500, 256, 0, stream>>>(Part, PT, Xc);

  expand_kernel<<<125000, 256, 0, stream>>>(Xc, (float4*)d_out);
}

// Round 4
// 739.971 us; speedup vs baseline: 1.1859x; 1.1859x over previous
//
#include <hip/hip_runtime.h>
#include <math.h>

constexpr int S = 200;    // base dim
constexpr int NBATCH = 16;
constexpr int SS = S * S;         // 40000
constexpr int FLAT = S * NBATCH;  // 3200
constexpr int SLICE = S * FLAT;   // 640000 complex per GEMM output

// ---------------- threefry2x32 (JAX-compatible, 20 rounds) ----------------
struct TFOut { unsigned a, b; };

__host__ __device__ constexpr TFOut tf2x32(unsigned k0, unsigned k1,
                                           unsigned x0, unsigned x1) {
  unsigned ks2 = k0 ^ k1 ^ 0x1BD11BDAu;
  unsigned ks[3] = {k0, k1, ks2};
  const int R0[4] = {13, 15, 26, 6};
  const int R1[4] = {17, 29, 16, 24};
  x0 += ks[0]; x1 += ks[1];
  for (int i = 0; i < 5; ++i) {
    const int* R = (i & 1) ? R1 : R0;
    for (int j = 0; j < 4; ++j) {
      x0 += x1;
      x1 = (x1 << R[j]) | (x1 >> (32 - R[j]));
      x1 ^= x0;
    }
    x0 += ks[(i + 1) % 3];
    x1 += ks[(i + 2) % 3] + (unsigned)(i + 1);
  }
  return {x0, x1};
}

constexpr TFOut KEY1 = tf2x32(0u, 42u, 0u, 0u);  // phase key
constexpr TFOut KEY2 = tf2x32(0u, 42u, 0u, 1u);  // intensity key

// ---------------- gumbel helpers ----------------
__device__ inline float bits_to_u(unsigned bits) {
  float f = __uint_as_float((bits >> 9) | 0x3f800000u) - 1.0f;
  f = f + 1e-10f;
  return fmaxf(1e-10f, f);
}

// exact path (baseline-identical): each log correctly rounded via double
__device__ inline float u_to_g_exact(float u) {
  float l1 = (float)log((double)u);
  float l2 = (float)log((double)(-l1));
  return -l2;
}

// fast path: ocml logf (<=1 ulp); |g_fast - g_exact| <~ 2.3e-6
__device__ inline float u_to_g_fast(float u) {
  float l1 = logf(u);
  float l2 = logf(-l1);
  return -l2;
}

__device__ inline unsigned ordf(float f) {
  unsigned u = __float_as_uint(f);
  return (u & 0x80000000u) ? ~u : (u | 0x80000000u);
}
__device__ inline float unordf(unsigned u) {
  return (u & 0x80000000u) ? __uint_as_float(u ^ 0x80000000u)
                           : __uint_as_float(~u);
}
__device__ inline unsigned long long packcand(float val, int p) {
  return ((unsigned long long)ordf(val) << 32) | (unsigned)(255 - p);
}
__device__ inline unsigned long long umax64(unsigned long long a,
                                            unsigned long long b) {
  return a > b ? a : b;
}
__device__ inline unsigned long long wave_max_ull(unsigned long long v) {
#pragma unroll
  for (int s = 32; s > 0; s >>= 1)
    v = umax64(v, (unsigned long long)__shfl_xor((unsigned long long)v, s, 64));
  return v;
}

// one block per pixel; 256 threads = 256 gumbel channels; shuffle reductions
__global__ __launch_bounds__(256) void gumbel_kernel(
    const float* __restrict__ voltage, const float* __restrict__ phase_func,
    const float* __restrict__ intensity_func, float2* __restrict__ PT) {
  const int q = blockIdx.x;
  const int p = threadIdx.x;
  const int wave = p >> 6, lane = p & 63;
  const unsigned idx = (unsigned)q * 256u + (unsigned)p;
  const float v = voltage[(size_t)q * 256 + p];
  TFOut r1 = tf2x32(KEY1.a, KEY1.b, 0u, idx);
  TFOut r2 = tf2x32(KEY2.a, KEY2.b, 0u, idx);
  const float u1 = bits_to_u(r1.a ^ r1.b);
  const float u2 = bits_to_u(r2.a ^ r2.b);
  const float c1a = (v + u_to_g_fast(u1)) * 0.1f;
  const float c2a = (v + u_to_g_fast(u2)) * 0.1f;

  __shared__ unsigned long long wred[2][4];
  __shared__ int wcnt[2][4];

  // pass 1: fast-value max (packed with index; tie -> low idx)
  unsigned long long pk1 = wave_max_ull(packcand(c1a, p));
  unsigned long long pk2 = wave_max_ull(packcand(c2a, p));
  if (lane == 0) { wred[0][wave] = pk1; wred[1][wave] = pk2; }
  __syncthreads();
  unsigned long long b1 = umax64(umax64(wred[0][0], wred[0][1]),
                                 umax64(wred[0][2], wred[0][3]));
  unsigned long long b2 = umax64(umax64(wred[1][0], wred[1][1]),
                                 umax64(wred[1][2], wred[1][3]));
  const float eps = 1e-5f;  // >> 2x fast-path error bound (~4.6e-7 in c)
  const bool q1 = c1a >= unordf((unsigned)(b1 >> 32)) - eps;
  const bool q2 = c2a >= unordf((unsigned)(b2 >> 32)) - eps;
  unsigned long long bal1 = __ballot(q1);
  unsigned long long bal2 = __ballot(q2);
  if (lane == 0) { wcnt[0][wave] = __popcll(bal1); wcnt[1][wave] = __popcll(bal2); }
  __syncthreads();
  const int n1 = wcnt[0][0] + wcnt[0][1] + wcnt[0][2] + wcnt[0][3];
  const int n2 = wcnt[1][0] + wcnt[1][1] + wcnt[1][2] + wcnt[1][3];

  unsigned long long w1 = b1, w2 = b2;  // sole qualifier == exact winner
  if (n1 > 1 || n2 > 1) {  // block-uniform rare path (~0.5% of blocks)
    unsigned long long e1 = q1 ? packcand((v + u_to_g_exact(u1)) / 10.0f, p) : 0ull;
    unsigned long long e2 = q2 ? packcand((v + u_to_g_exact(u2)) / 10.0f, p) : 0ull;
    e1 = wave_max_ull(e1);
    e2 = wave_max_ull(e2);
    if (lane == 0) { wred[0][wave] = e1; wred[1][wave] = e2; }
    __syncthreads();
    w1 = umax64(umax64(wred[0][0], wred[0][1]), umax64(wred[0][2], wred[0][3]));
    w2 = umax64(umax64(wred[1][0], wred[1][1]), umax64(wred[1][2], wred[1][3]));
  }
  if (p == 0) {
    int i1 = 255 - (int)(w1 & 0xFFFFFFFFull);
    int i2 = 255 - (int)(w2 & 0xFFFFFFFFull);
    float phi = phase_func[i1];
    float amp = intensity_func[i2] * 6.0f;
    PT[q] = make_float2(amp * cosf(phi), amp * sinf(phi));
  }
}

// ---------------- DFT tables ----------------
// only 200 distinct twiddles: tw[m] = exp(-i 2 pi m / 200), double-accurate
__global__ __launch_bounds__(256) void build_tw(float2* __restrict__ tw) {
  int m = threadIdx.x;
  if (m < S) {
    double ang = -2.0 * 3.1415926535897932384626433832795 * (double)m / (double)S;
    tw[m] = make_float2((float)cos(ang), (float)sin(ang));
  }
}

__global__ __launch_bounds__(256) void build_tables(
    const float* __restrict__ h_real, const float* __restrict__ h_imag,
    const float2* __restrict__ tw, float2* __restrict__ F,
    float2* __restrict__ G, float2* __restrict__ Hc) {
  int idx = blockIdx.x * 256 + threadIdx.x;
  if (idx >= SS) return;
  int j = idx / S;
  int k = idx - j * S;
  int m = (j * k) % S;
  float2 t = tw[m];
  F[idx] = t;
  G[idx] = make_float2(t.x * 0.005f, -t.y * 0.005f);  // conj/200
  Hc[idx] = make_float2(h_real[idx], h_imag[idx]);
}

// ---------------- K-split flat complex GEMM ----------------
// APERM=false: C(200 x 3200) = A(200x200) @ B'(200x3200),
//   B'[k][b*200+n] = B[b*40000 + k*200 + n]
// APERM=true : C(3200 x 200) = A'(3200x200) @ B(200x200),
//   A'[b*200+i][k] = A[i*3200 + b*200 + k]
// MODE: 0 = plain B; 1 = B .* Hm (elementwise complex); 2 = B from re/im planes
template <bool APERM, int MODE>
__global__ __launch_bounds__(256) void cgemm_ks(
    const float2* __restrict__ A, const float2* __restrict__ B,
    const float* __restrict__ Bre, const float* __restrict__ Bim,
    const float2* __restrict__ Hm, float2* __restrict__ Cp,
    int M, int N, int K, int KSlice) {
  __shared__ __align__(16) float2 As[16][64];  // [k][m]
  __shared__ __align__(16) float2 Bs[16][64];  // [k][n]
  const int tid = threadIdx.x;
  const int rowBase = blockIdx.x * 64;
  const int colBase = blockIdx.y * 64;
  const int Kbeg = blockIdx.z * KSlice;
  const int Kend = min(Kbeg + KSlice, K);

  const int a_m = tid >> 2;          // 0..63
  const int a_k4 = (tid & 3) * 4;    // 0,4,8,12
  const int b_k = tid >> 4;          // 0..15
  const int b_n4 = (tid & 15) * 4;   // 0..60
  const int tx4 = (tid & 15) * 4;
  const int ty4 = (tid >> 4) * 4;

  long arow;
  bool arow_ok;
  {
    int gm = rowBase + a_m;
    if (APERM) {
      int b = gm / S, i = gm - b * S;  // gm < 3200 (grid exact)
      arow = (long)i * FLAT + (long)b * S;
      arow_ok = true;
    } else {
      arow_ok = (gm < M);
      arow = (long)gm * S;
    }
  }
  long bcol;        // float2-element base for MODE 0/1 (or scalar base, MODE 2)
  int nmod = 0;
  bool bcol_ok;
  {
    int gn = colBase + b_n4;
    if (APERM) {
      bcol = gn;
      bcol_ok = (gn < N);
    } else {
      int b = gn / S;
      nmod = gn - b * S;  // 4-aligned, never straddles (200 % 4 == 0)
      bcol = (long)b * SS + nmod;
      bcol_ok = true;
    }
  }

  float2 acc[4][4];
#pragma unroll
  for (int i = 0; i < 4; ++i)
#pragma unroll
    for (int j = 0; j < 4; ++j) acc[i][j] = make_float2(0.f, 0.f);

  for (int k0 = Kbeg; k0 < Kend; k0 += 16) {
    const int gka = k0 + a_k4;
    float4 av0 = {0, 0, 0, 0}, av1 = {0, 0, 0, 0};
    if (arow_ok) {
      if (gka < Kend) av0 = *(const float4*)&A[arow + gka];
      if (gka + 2 < Kend) av1 = *(const float4*)&A[arow + gka + 2];
    }
    const int gkb = k0 + b_k;
    float4 bv0 = {0, 0, 0, 0}, bv1 = {0, 0, 0, 0};
    if (bcol_ok && gkb < Kend) {
      if (MODE == 2) {
        const long off = bcol + (long)gkb * S;
        float4 re4 = *(const float4*)&Bre[off];
        float4 im4 = *(const float4*)&Bim[off];
        bv0 = make_float4(re4.x, im4.x, re4.y, im4.y);
        bv1 = make_float4(re4.z, im4.z, re4.w, im4.w);
      } else {
        const float2* bp = &B[bcol + (long)gkb * S];
        bv0 = *(const float4*)bp;
        bv1 = *(const float4*)(bp + 2);
        if (MODE == 1) {
          const float2* hp = &Hm[(long)gkb * S + nmod];
          float4 h0 = *(const float4*)hp;
          float4 h1 = *(const float4*)(hp + 2);
          bv0 = make_float4(bv0.x * h0.x - bv0.y * h0.y, bv0.x * h0.y + bv0.y * h0.x,
                            bv0.z * h0.z - bv0.w * h0.w, bv0.z * h0.w + bv0.w * h0.z);
          bv1 = make_float4(bv1.x * h1.x - bv1.y * h1.y, bv1.x * h1.y + bv1.y * h1.x,
                            bv1.z * h1.z - bv1.w * h1.w, bv1.z * h1.w + bv1.w * h1.z);
        }
      }
    }
    __syncthreads();  // prior compute done before LDS overwrite
    As[a_k4 + 0][a_m] = make_float2(av0.x, av0.y);
    As[a_k4 + 1][a_m] = make_float2(av0.z, av0.w);
    As[a_k4 + 2][a_m] = make_float2(av1.x, av1.y);
    As[a_k4 + 3][a_m] = make_float2(av1.z, av1.w);
    *(float4*)&Bs[b_k][b_n4] = bv0;
    *(float4*)&Bs[b_k][b_n4 + 2] = bv1;
    __syncthreads();
#pragma unroll
    for (int kk = 0; kk < 16; ++kk) {
      float4 aA = *(const float4*)&As[kk][ty4];
      float4 aB = *(const float4*)&As[kk][ty4 + 2];
      float4 bA = *(const float4*)&Bs[kk][tx4];
      float4 bB = *(const float4*)&Bs[kk][tx4 + 2];
      float2 a[4] = {{aA.x, aA.y}, {aA.z, aA.w}, {aB.x, aB.y}, {aB.z, aB.w}};
      float2 b[4] = {{bA.x, bA.y}, {bA.z, bA.w}, {bB.x, bB.y}, {bB.z, bB.w}};
#pragma unroll
      for (int i = 0; i < 4; ++i)
#pragma unroll
        for (int j = 0; j < 4; ++j) {
          acc[i][j].x = fmaf(a[i].x, b[j].x, fmaf(-a[i].y, b[j].y, acc[i][j].x));
          acc[i][j].y = fmaf(a[i].x, b[j].y, fmaf(a[i].y, b[j].x, acc[i][j].y));
        }
    }
  }
  float2* Co = Cp + (long)blockIdx.z * SLICE;
#pragma unroll
  for (int rr = 0; rr < 4; ++rr) {
    const int r = rowBase + ty4 + rr;
    const int cb = colBase + tx4;
    if (r < M && cb < N) {
      *(float4*)&Co[(long)r * N + cb] = make_float4(acc[rr][0].x, acc[rr][0].y,
                                                    acc[rr][1].x, acc[rr][1].y);
      *(float4*)&Co[(long)r * N + cb + 2] = make_float4(acc[rr][2].x, acc[rr][2].y,
                                                        acc[rr][3].x, acc[rr][3].y);
    }
  }
}

// ---------------- K-split reduction ----------------
__global__ __launch_bounds__(256) void reduce4(
    const float4* __restrict__ P, float4* __restrict__ D) {
  int i = blockIdx.x * 256 + threadIdx.x;  // 320000 float4 = 640000 complex
  if (i >= SLICE / 2) return;
  float4 a = P[i], b = P[i + SLICE / 2], c = P[i + SLICE], d = P[i + 3 * SLICE / 2];
  D[i] = make_float4(a.x + b.x + c.x + d.x, a.y + b.y + c.y + d.y,
                     a.z + b.z + c.z + d.z, a.w + b.w + c.w + d.w);
}

// last reduce: also multiply by per-pixel phase-trig PT
__global__ __launch_bounds__(256) void reduce4_pt(
    const float2* __restrict__ P, const float2* __restrict__ PT,
    float2* __restrict__ D) {
  int i = blockIdx.x * 256 + threadIdx.x;  // 640000 complex
  if (i >= SLICE) return;
  float2 a = P[i], b = P[i + SLICE], c = P[i + 2 * SLICE], d = P[i + 3 * SLICE];
  float sx = a.x + b.x + c.x + d.x;
  float sy = a.y + b.y + c.y + d.y;
  float2 pt = PT[i % SS];  // rows are b*200+i, cols j -> pixel = i%40000
  D[i] = make_float2(sx * pt.x - sy * pt.y, sx * pt.y + sy * pt.x);
}

// ---------------- 10x pixel expansion (pure replicate) ----------------
__global__ __launch_bounds__(256) void expand_kernel(
    const float2* __restrict__ Xc, float4* __restrict__ out) {
  unsigned q = blockIdx.x * 256u + threadIdx.x;  // < 32,000,000 exact
  unsigned p0 = q * 2u;
  unsigned b = p0 / 4000000u;
  unsigned rem = p0 - b * 4000000u;
  unsigned r = rem / 2000u;
  unsigned c0 = rem - r * 2000u;
  unsigned i = r / 10u;
  unsigned dr = r - i * 10u;
  float4 o = {0.f, 0.f, 0.f, 0.f};
  if (dr - 1u <= 7u) {  // dr in [1,8]
    unsigned j = c0 / 10u;
    unsigned dc = c0 - j * 10u;  // even: 0,2,4,6,8
    float2 xv = Xc[b * 40000u + i * 200u + j];
    if (dc != 0u) { o.x = xv.x; o.y = xv.y; }
    if (dc != 8u) { o.z = xv.x; o.w = xv.y; }
  }
  out[q] = o;
}

// ---------------- launch ----------------
extern "C" void kernel_launch(void* const* d_in, const int* in_sizes, int n_in,
                              void* d_out, int out_size, void* d_ws, size_t ws_size,
                              hipStream_t stream) {
  const float* waves_real = (const float*)d_in[0];
  const float* waves_imag = (const float*)d_in[1];
  const float* h_real = (const float*)d_in[2];
  const float* h_imag = (const float*)d_in[3];
  const float* voltage = (const float*)d_in[4];
  const float* phase_func = (const float*)d_in[5];
  const float* intensity_func = (const float*)d_in[6];

  float2* TW   = (float2*)d_ws;       // 200 (pad to 256)
  float2* F    = TW + 256;            // 40000
  float2* G    = F + SS;              // 40000
  float2* Hc   = G + SS;              // 40000
  float2* PT   = Hc + SS;             // 40000
  float2* T1   = PT + SS;             // 640000 (200 x 3200)
  float2* T2   = T1 + SLICE;          // 640000 (rows b*200+k, cols n)
  float2* T4   = T2 + SLICE;          // 640000 (200 x 3200)
  float2* Xc   = T4 + SLICE;          // 640000 (rows b*200+i, cols j)
  float2* Part = Xc + SLICE;          // 4 x 640000 partials (~42 MB total ws)

  build_tw<<<1, 256, 0, stream>>>(TW);
  build_tables<<<157, 256, 0, stream>>>(h_real, h_imag, TW, F, G, Hc);
  gumbel_kernel<<<40000, 256, 0, stream>>>(voltage, phase_func, intensity_func, PT);

  dim3 gB(4, 50, 4);   // rows(200) x cols(3200) x ksplit
  dim3 gA(50, 4, 4);   // rows(3200) x cols(200) x ksplit

  // T1 = F @ W'            (fft axis 0; W interleaved from re/im planes)
  cgemm_ks<false, 2><<<gB, 256, 0, stream>>>(F, nullptr, waves_real, waves_imag,
                                             nullptr, Part, S, FLAT, S, 50);
  reduce4<<<1250, 256, 0, stream>>>((const float4*)Part, (float4*)T1);
  // T2 = T1' @ F           (fft axis 1, batch-permuted rows)
  cgemm_ks<true, 0><<<gA, 256, 0, stream>>>(T1, F, nullptr, nullptr, nullptr,
                                            Part, FLAT, S, S, 50);
  reduce4<<<1250, 256, 0, stream>>>((const float4*)Part, (float4*)T2);
  // T4 = G @ (T2' .* h)    (ifft axis 0, h fused)
  cgemm_ks<false, 1><<<gB, 256, 0, stream>>>(G, T2, nullptr, nullptr, Hc,
                                             Part, S, FLAT, S, 50);
  reduce4<<<1250, 256, 0, stream>>>((const float4*)Part, (float4*)T4);
  // Xc = (T4' @ G) .* PT   (ifft axis 1 + phase-trig fused into reduce)
  cgemm_ks<true, 0><<<gA, 256, 0, stream>>>(T4, G, nullptr, nullptr, nullptr,
                                            Part, FLAT, S, S, 50);
  reduce4_pt<<<2500, 256, 0, stream>>>(Part, PT, Xc);

  expand_kernel<<<125000, 256, 0, stream>>>(Xc, (float4*)d_out);
}

// Round 5
// 681.838 us; speedup vs baseline: 1.2870x; 1.0853x over previous
//
#include <hip/hip_runtime.h>
#include <math.h>

constexpr int S = 200;
constexpr int SS = S * S;           // 40000
constexpr int FLAT = 3200;          // 16 batches * 200
constexpr int SLICE = 640000;       // 200*3200 complex
constexpr int MP = 256;             // padded M for planes
constexpr int KP = 224;             // padded K (7 chunks of 32)
constexpr int PS = MP * KP;         // 57344 elements per bf16 plane

typedef short short8 __attribute__((ext_vector_type(8)));
typedef float float4v __attribute__((ext_vector_type(4)));

// ---------------- threefry2x32 (JAX-compatible, 20 rounds) ----------------
struct TFOut { unsigned a, b; };

__host__ __device__ constexpr TFOut tf2x32(unsigned k0, unsigned k1,
                                           unsigned x0, unsigned x1) {
  unsigned ks2 = k0 ^ k1 ^ 0x1BD11BDAu;
  unsigned ks[3] = {k0, k1, ks2};
  const int R0[4] = {13, 15, 26, 6};
  const int R1[4] = {17, 29, 16, 24};
  x0 += ks[0]; x1 += ks[1];
  for (int i = 0; i < 5; ++i) {
    const int* R = (i & 1) ? R1 : R0;
    for (int j = 0; j < 4; ++j) {
      x0 += x1;
      x1 = (x1 << R[j]) | (x1 >> (32 - R[j]));
      x1 ^= x0;
    }
    x0 += ks[(i + 1) % 3];
    x1 += ks[(i + 2) % 3] + (unsigned)(i + 1);
  }
  return {x0, x1};
}

constexpr TFOut KEY1 = tf2x32(0u, 42u, 0u, 0u);
constexpr TFOut KEY2 = tf2x32(0u, 42u, 0u, 1u);

// ---------------- gumbel helpers ----------------
__device__ inline float bits_to_u(unsigned bits) {
  float f = __uint_as_float((bits >> 9) | 0x3f800000u) - 1.0f;
  f = f + 1e-10f;
  return fmaxf(1e-10f, f);
}
__device__ inline float u_to_g_exact(float u) {
  float l1 = (float)log((double)u);
  float l2 = (float)log((double)(-l1));
  return -l2;
}
__device__ inline float u_to_g_fast(float u) {
  float l1 = logf(u);
  float l2 = logf(-l1);
  return -l2;
}
__device__ inline unsigned ordf(float f) {
  unsigned u = __float_as_uint(f);
  return (u & 0x80000000u) ? ~u : (u | 0x80000000u);
}
__device__ inline float unordf(unsigned u) {
  return (u & 0x80000000u) ? __uint_as_float(u ^ 0x80000000u)
                           : __uint_as_float(~u);
}
__device__ inline unsigned long long packcand(float val, int p) {
  return ((unsigned long long)ordf(val) << 32) | (unsigned)(255 - p);
}
__device__ inline unsigned long long umax64(unsigned long long a,
                                            unsigned long long b) {
  return a > b ? a : b;
}
__device__ inline unsigned long long wave_max_ull(unsigned long long v) {
#pragma unroll
  for (int s = 32; s > 0; s >>= 1)
    v = umax64(v, (unsigned long long)__shfl_xor((unsigned long long)v, s, 64));
  return v;
}

__global__ __launch_bounds__(256) void gumbel_kernel(
    const float* __restrict__ voltage, const float* __restrict__ phase_func,
    const float* __restrict__ intensity_func, float2* __restrict__ PT) {
  const int q = blockIdx.x;
  const int p = threadIdx.x;
  const int wave = p >> 6, lane = p & 63;
  const unsigned idx = (unsigned)q * 256u + (unsigned)p;
  const float v = voltage[(size_t)q * 256 + p];
  TFOut r1 = tf2x32(KEY1.a, KEY1.b, 0u, idx);
  TFOut r2 = tf2x32(KEY2.a, KEY2.b, 0u, idx);
  const float u1 = bits_to_u(r1.a ^ r1.b);
  const float u2 = bits_to_u(r2.a ^ r2.b);
  const float c1a = (v + u_to_g_fast(u1)) * 0.1f;
  const float c2a = (v + u_to_g_fast(u2)) * 0.1f;

  __shared__ unsigned long long wred[2][4];
  __shared__ int wcnt[2][4];

  unsigned long long pk1 = wave_max_ull(packcand(c1a, p));
  unsigned long long pk2 = wave_max_ull(packcand(c2a, p));
  if (lane == 0) { wred[0][wave] = pk1; wred[1][wave] = pk2; }
  __syncthreads();
  unsigned long long b1 = umax64(umax64(wred[0][0], wred[0][1]),
                                 umax64(wred[0][2], wred[0][3]));
  unsigned long long b2 = umax64(umax64(wred[1][0], wred[1][1]),
                                 umax64(wred[1][2], wred[1][3]));
  const float eps = 1e-5f;
  const bool q1 = c1a >= unordf((unsigned)(b1 >> 32)) - eps;
  const bool q2 = c2a >= unordf((unsigned)(b2 >> 32)) - eps;
  unsigned long long bal1 = __ballot(q1);
  unsigned long long bal2 = __ballot(q2);
  if (lane == 0) { wcnt[0][wave] = __popcll(bal1); wcnt[1][wave] = __popcll(bal2); }
  __syncthreads();
  const int n1 = wcnt[0][0] + wcnt[0][1] + wcnt[0][2] + wcnt[0][3];
  const int n2 = wcnt[1][0] + wcnt[1][1] + wcnt[1][2] + wcnt[1][3];

  unsigned long long w1 = b1, w2 = b2;
  if (n1 > 1 || n2 > 1) {  // rare block-uniform exact path
    unsigned long long e1 = q1 ? packcand((v + u_to_g_exact(u1)) / 10.0f, p) : 0ull;
    unsigned long long e2 = q2 ? packcand((v + u_to_g_exact(u2)) / 10.0f, p) : 0ull;
    e1 = wave_max_ull(e1);
    e2 = wave_max_ull(e2);
    if (lane == 0) { wred[0][wave] = e1; wred[1][wave] = e2; }
    __syncthreads();
    w1 = umax64(umax64(wred[0][0], wred[0][1]), umax64(wred[0][2], wred[0][3]));
    w2 = umax64(umax64(wred[1][0], wred[1][1]), umax64(wred[1][2], wred[1][3]));
  }
  if (p == 0) {
    int i1 = 255 - (int)(w1 & 0xFFFFFFFFull);
    int i2 = 255 - (int)(w2 & 0xFFFFFFFFull);
    float phi = phase_func[i1];
    float amp = intensity_func[i2] * 6.0f;
    PT[q] = make_float2(amp * cosf(phi), amp * sinf(phi));
  }
}

// ---------------- tables ----------------
__global__ __launch_bounds__(256) void build_tw(float2* __restrict__ tw) {
  int m = threadIdx.x;
  if (m < S) {
    double ang = -2.0 * 3.1415926535897932384626433832795 * (double)m / (double)S;
    tw[m] = make_float2((float)cos(ang), (float)sin(ang));
  }
}

__device__ inline unsigned short bf16_rne(float x) {
  unsigned u = __float_as_uint(x);
  return (unsigned short)((u + 0x7FFFu + ((u >> 16) & 1u)) >> 16);
}
__device__ inline void split_bf16(float x, unsigned short& h, unsigned short& l) {
  h = bf16_rne(x);
  float hf = __uint_as_float(((unsigned)h) << 16);
  l = bf16_rne(x - hf);
}

// bf16 hi/lo planes of F and G: 8 planes [MP][KP]
__global__ __launch_bounds__(256) void build_planes(
    const float2* __restrict__ tw, unsigned short* __restrict__ PL) {
  int idx = blockIdx.x * 256 + threadIdx.x;  // 224*256 = 57344 = MP*KP exact
  int m = idx / KP, k = idx - (idx / KP) * KP;
  float fr = 0.f, fi = 0.f;
  if (m < S && k < S) {
    float2 t = tw[(m * k) % S];
    fr = t.x; fi = t.y;
  }
  unsigned short h, l;
  split_bf16(fr, h, l);          PL[0 * PS + idx] = h; PL[1 * PS + idx] = l;
  split_bf16(fi, h, l);          PL[2 * PS + idx] = h; PL[3 * PS + idx] = l;
  split_bf16(fr * 0.005f, h, l); PL[4 * PS + idx] = h; PL[5 * PS + idx] = l;
  split_bf16(-fi * 0.005f, h, l);PL[6 * PS + idx] = h; PL[7 * PS + idx] = l;
}

// transposed h table: HT[n][k] = h[k][n]
__global__ __launch_bounds__(256) void build_ht(
    const float* __restrict__ h_real, const float* __restrict__ h_imag,
    float2* __restrict__ HT) {
  int idx = blockIdx.x * 256 + threadIdx.x;
  if (idx >= SS) return;
  int k = idx / S, n = idx - (idx / S) * S;
  HT[n * S + k] = make_float2(h_real[idx], h_imag[idx]);
}

// ---------------- MFMA split-bf16 GEMM ----------------
// out[m][(b,n)] = sum_k Op[m][k] * Bop[k][(b,n)], Op = F or G (bf16 planes).
// MODE 0: Bop = waves[b][k][n] (re/im planes)
// MODE 1: Bop = Sprev[b*200+n][k]
// MODE 2: Bop = Sprev[b*200+n][k] * h[k][n]  (via HT[n][k])
// Output stored Sout[(b*200+m)*200 + n]. FINAL: multiply by PT[n*200+m].
template <int MODE, bool FINAL>
__global__ __launch_bounds__(256) void gemm_mfma(
    const unsigned short* __restrict__ APL, const float* __restrict__ Wre,
    const float* __restrict__ Wim, const float2* __restrict__ Sprev,
    const float2* __restrict__ HT, const float2* __restrict__ PT,
    float2* __restrict__ Sout) {
  __shared__ short As[4][64][40];  // planes rh,rl,ih,il ; [m][k] k-contig
  __shared__ short Bs[4][64][40];  // planes ; [n][k] k-contig
  const int tid = threadIdx.x;
  const int wave = tid >> 6, lane = tid & 63, quad = lane >> 4, l15 = lane & 15;
  const int mb = blockIdx.x * 64;  // 0,64,128,192 (padded M=256)
  const int cb = blockIdx.y * 64;  // flat col base, N=3200

  // staging roles
  const int sp = tid >> 6;         // A plane
  const int sm = tid & 63;         // A row
  const int sn = tid & 63;         // B col-within-tile
  const int sk0 = (tid >> 6) * 8;  // B k sub-chunk
  const int cB = cb + sn;
  const int bB = cB / S;
  const int nB = cB - bB * S;

  float4v accRR[2][2], accII[2][2], accRI[2][2], accIR[2][2];
#pragma unroll
  for (int i = 0; i < 2; ++i)
#pragma unroll
    for (int j = 0; j < 2; ++j) {
      accRR[i][j] = (float4v){0.f, 0.f, 0.f, 0.f};
      accII[i][j] = (float4v){0.f, 0.f, 0.f, 0.f};
      accRI[i][j] = (float4v){0.f, 0.f, 0.f, 0.f};
      accIR[i][j] = (float4v){0.f, 0.f, 0.f, 0.f};
    }

  for (int ch = 0; ch < 7; ++ch) {
    const int kc = ch * 32;
    // A: copy precomputed bf16 plane chunk (zero-padded globally)
    const unsigned short* ap = APL + sp * PS + (mb + sm) * KP + kc;
    short8 a0 = *(const short8*)(ap + 0);
    short8 a1 = *(const short8*)(ap + 8);
    short8 a2 = *(const short8*)(ap + 16);
    short8 a3 = *(const short8*)(ap + 24);

    // B: load fp32 + convert to 4 bf16 planes
    unsigned short brh[8], brl[8], bih[8], bil[8];
    const bool kok = (kc + sk0) < S;  // whole 8-group in/out of range
    float re[8], im[8];
#pragma unroll
    for (int j = 0; j < 8; ++j) { re[j] = 0.f; im[j] = 0.f; }
    if (kok) {
      if (MODE == 0) {
#pragma unroll
        for (int j = 0; j < 8; ++j) {
          int k = kc + sk0 + j;
          re[j] = Wre[(long)bB * SS + k * S + nB];
          im[j] = Wim[(long)bB * SS + k * S + nB];
        }
      } else {
        const float2* bp = &Sprev[(long)(bB * S + nB) * S + kc + sk0];
#pragma unroll
        for (int j = 0; j < 8; ++j) { re[j] = bp[j].x; im[j] = bp[j].y; }
        if (MODE == 2) {
          const float2* hp = &HT[(long)nB * S + kc + sk0];
#pragma unroll
          for (int j = 0; j < 8; ++j) {
            float2 hv = hp[j];
            float tr = re[j] * hv.x - im[j] * hv.y;
            im[j] = re[j] * hv.y + im[j] * hv.x;
            re[j] = tr;
          }
        }
      }
    }
#pragma unroll
    for (int j = 0; j < 8; ++j) {
      split_bf16(re[j], brh[j], brl[j]);
      split_bf16(im[j], bih[j], bil[j]);
    }

    __syncthreads();  // previous chunk's frag reads complete
    *(short8*)&As[sp][sm][0] = a0;
    *(short8*)&As[sp][sm][8] = a1;
    *(short8*)&As[sp][sm][16] = a2;
    *(short8*)&As[sp][sm][24] = a3;
    short8 v0, v1, v2, v3;
#pragma unroll
    for (int j = 0; j < 8; ++j) {
      v0[j] = (short)brh[j]; v1[j] = (short)brl[j];
      v2[j] = (short)bih[j]; v3[j] = (short)bil[j];
    }
    *(short8*)&Bs[0][sn][sk0] = v0;
    *(short8*)&Bs[1][sn][sk0] = v1;
    *(short8*)&Bs[2][sn][sk0] = v2;
    *(short8*)&Bs[3][sn][sk0] = v3;
    __syncthreads();

    // fragments: A[m=l15][k=quad*8+j], B[k=quad*8+j][n=l15]
    short8 Arh[2], Arl[2], Aih[2], Ail[2], Brh[2], Brl[2], Bih[2], Bil[2];
#pragma unroll
    for (int t = 0; t < 2; ++t) {
      int mr = (wave & 1) * 32 + t * 16 + l15;
      Arh[t] = *(const short8*)&As[0][mr][quad * 8];
      Arl[t] = *(const short8*)&As[1][mr][quad * 8];
      Aih[t] = *(const short8*)&As[2][mr][quad * 8];
      Ail[t] = *(const short8*)&As[3][mr][quad * 8];
      int nr = (wave >> 1) * 32 + t * 16 + l15;
      Brh[t] = *(const short8*)&Bs[0][nr][quad * 8];
      Brl[t] = *(const short8*)&Bs[1][nr][quad * 8];
      Bih[t] = *(const short8*)&Bs[2][nr][quad * 8];
      Bil[t] = *(const short8*)&Bs[3][nr][quad * 8];
    }
#pragma unroll
    for (int mi = 0; mi < 2; ++mi)
#pragma unroll
      for (int ni = 0; ni < 2; ++ni) {
        accRR[mi][ni] = __builtin_amdgcn_mfma_f32_16x16x32_bf16(Arh[mi], Brh[ni], accRR[mi][ni], 0, 0, 0);
        accRR[mi][ni] = __builtin_amdgcn_mfma_f32_16x16x32_bf16(Arh[mi], Brl[ni], accRR[mi][ni], 0, 0, 0);
        accRR[mi][ni] = __builtin_amdgcn_mfma_f32_16x16x32_bf16(Arl[mi], Brh[ni], accRR[mi][ni], 0, 0, 0);
        accII[mi][ni] = __builtin_amdgcn_mfma_f32_16x16x32_bf16(Aih[mi], Bih[ni], accII[mi][ni], 0, 0, 0);
        accII[mi][ni] = __builtin_amdgcn_mfma_f32_16x16x32_bf16(Aih[mi], Bil[ni], accII[mi][ni], 0, 0, 0);
        accII[mi][ni] = __builtin_amdgcn_mfma_f32_16x16x32_bf16(Ail[mi], Bih[ni], accII[mi][ni], 0, 0, 0);
        accRI[mi][ni] = __builtin_amdgcn_mfma_f32_16x16x32_bf16(Arh[mi], Bih[ni], accRI[mi][ni], 0, 0, 0);
        accRI[mi][ni] = __builtin_amdgcn_mfma_f32_16x16x32_bf16(Arh[mi], Bil[ni], accRI[mi][ni], 0, 0, 0);
        accRI[mi][ni] = __builtin_amdgcn_mfma_f32_16x16x32_bf16(Arl[mi], Bih[ni], accRI[mi][ni], 0, 0, 0);
        accIR[mi][ni] = __builtin_amdgcn_mfma_f32_16x16x32_bf16(Aih[mi], Brh[ni], accIR[mi][ni], 0, 0, 0);
        accIR[mi][ni] = __builtin_amdgcn_mfma_f32_16x16x32_bf16(Aih[mi], Brl[ni], accIR[mi][ni], 0, 0, 0);
        accIR[mi][ni] = __builtin_amdgcn_mfma_f32_16x16x32_bf16(Ail[mi], Brh[ni], accIR[mi][ni], 0, 0, 0);
      }
  }

  // epilogue: C/D layout col=l15, row=quad*4+r
#pragma unroll
  for (int mi = 0; mi < 2; ++mi)
#pragma unroll
    for (int ni = 0; ni < 2; ++ni) {
      int cg = cb + (wave >> 1) * 32 + ni * 16 + l15;
      int b = cg / S;
      int n = cg - b * S;
#pragma unroll
      for (int r = 0; r < 4; ++r) {
        int m = mb + (wave & 1) * 32 + mi * 16 + quad * 4 + r;
        if (m < S) {
          float Cr = accRR[mi][ni][r] - accII[mi][ni][r];
          float Ci = accRI[mi][ni][r] + accIR[mi][ni][r];
          if (FINAL) {
            float2 pt = PT[n * S + m];
            float tr = Cr * pt.x - Ci * pt.y;
            Ci = Cr * pt.y + Ci * pt.x;
            Cr = tr;
          }
          Sout[(long)(b * S + m) * S + n] = make_float2(Cr, Ci);
        }
      }
    }
}

// ---------------- 10x pixel expansion ----------------
// S4[(b*200+j)*200 + i] = X_b[i][j] (phase applied). out (16,2000,2000,2).
__global__ __launch_bounds__(256) void expand_kernel(
    const float2* __restrict__ S4, float4* __restrict__ out) {
  unsigned q = blockIdx.x * 256u + threadIdx.x;  // < 32,000,000 exact
  unsigned p0 = q * 2u;
  unsigned b = p0 / 4000000u;
  unsigned rem = p0 - b * 4000000u;
  unsigned r = rem / 2000u;
  unsigned c0 = rem - r * 2000u;
  unsigned i = r / 10u;
  unsigned dr = r - i * 10u;
  float4 o = {0.f, 0.f, 0.f, 0.f};
  if (dr - 1u <= 7u) {  // dr in [1,8]
    unsigned j = c0 / 10u;
    unsigned dc = c0 - j * 10u;  // even: 0,2,4,6,8
    float2 xv = S4[(b * 200u + j) * 200u + i];
    if (dc != 0u) { o.x = xv.x; o.y = xv.y; }
    if (dc != 8u) { o.z = xv.x; o.w = xv.y; }
  }
  out[q] = o;
}

// ---------------- launch ----------------
extern "C" void kernel_launch(void* const* d_in, const int* in_sizes, int n_in,
                              void* d_out, int out_size, void* d_ws, size_t ws_size,
                              hipStream_t stream) {
  const float* waves_real = (const float*)d_in[0];
  const float* waves_imag = (const float*)d_in[1];
  const float* h_real = (const float*)d_in[2];
  const float* h_imag = (const float*)d_in[3];
  const float* voltage = (const float*)d_in[4];
  const float* phase_func = (const float*)d_in[5];
  const float* intensity_func = (const float*)d_in[6];

  float2* TW = (float2*)d_ws;      // 256
  float2* HT = TW + 256;           // 40000
  float2* PT = HT + SS;            // 40000
  float2* S1 = PT + SS;            // 640000 each
  float2* S2 = S1 + SLICE;
  float2* S3 = S2 + SLICE;
  float2* S4 = S3 + SLICE;
  unsigned short* PL = (unsigned short*)(S4 + SLICE);  // 8 * 57344 bf16

  build_tw<<<1, 256, 0, stream>>>(TW);
  build_planes<<<224, 256, 0, stream>>>(TW, PL);
  build_ht<<<157, 256, 0, stream>>>(h_real, h_imag, HT);
  gumbel_kernel<<<40000, 256, 0, stream>>>(voltage, phase_func, intensity_func, PT);

  const unsigned short* FP = PL;           // F planes
  const unsigned short* GP = PL + 4 * PS;  // G planes
  dim3 g(4, 50);
  // S1[b*200+m][n] = T1_b[m][n],  T1_b = F @ W_b
  gemm_mfma<0, false><<<g, 256, 0, stream>>>(FP, waves_real, waves_imag,
                                             nullptr, nullptr, nullptr, S1);
  // S2[b*200+m][n] = T2_b[n][m],  T2_b = T1_b @ F  (computed as F @ T1_b^T)
  gemm_mfma<1, false><<<g, 256, 0, stream>>>(FP, nullptr, nullptr, S1,
                                             nullptr, nullptr, S2);
  // S3[b*200+m][n] = T4_b[m][n],  T4_b = G @ (T2_b .* h)
  gemm_mfma<2, false><<<g, 256, 0, stream>>>(GP, nullptr, nullptr, S2,
                                             HT, nullptr, S3);
  // S4[b*200+m][n] = X_b[n][m]*PT, X_b = T4_b @ G  (computed as G @ T4_b^T)
  gemm_mfma<1, true><<<g, 256, 0, stream>>>(GP, nullptr, nullptr, S3,
                                            nullptr, PT, S4);

  expand_kernel<<<125000, 256, 0, stream>>>(S4, (float4*)d_out);
}

// Round 7
// 635.312 us; speedup vs baseline: 1.3812x; 1.0732x over previous
//
#include <hip/hip_runtime.h>
#include <math.h>

constexpr int S = 200;
constexpr int SS = S * S;           // 40000
constexpr int SLICE = 640000;       // 200*3200 complex
constexpr int MP = 224;             // padded rows (7 tiles of 32)
constexpr int KP = 224;             // padded K (7 chunks of 32)
constexpr int PS = MP * KP;         // 50176 elements per bf16 plane

typedef short short8 __attribute__((ext_vector_type(8)));
typedef short short4v __attribute__((ext_vector_type(4)));
typedef float float4v __attribute__((ext_vector_type(4)));

// ---------------- threefry2x32 (JAX-compatible, 20 rounds) ----------------
struct TFOut { unsigned a, b; };

__host__ __device__ constexpr TFOut tf2x32(unsigned k0, unsigned k1,
                                           unsigned x0, unsigned x1) {
  unsigned ks2 = k0 ^ k1 ^ 0x1BD11BDAu;
  unsigned ks[3] = {k0, k1, ks2};
  const int R0[4] = {13, 15, 26, 6};
  const int R1[4] = {17, 29, 16, 24};
  x0 += ks[0]; x1 += ks[1];
  for (int i = 0; i < 5; ++i) {
    const int* R = (i & 1) ? R1 : R0;
    for (int j = 0; j < 4; ++j) {
      x0 += x1;
      x1 = (x1 << R[j]) | (x1 >> (32 - R[j]));
      x1 ^= x0;
    }
    x0 += ks[(i + 1) % 3];
    x1 += ks[(i + 2) % 3] + (unsigned)(i + 1);
  }
  return {x0, x1};
}

constexpr TFOut KEY1 = tf2x32(0u, 42u, 0u, 0u);
constexpr TFOut KEY2 = tf2x32(0u, 42u, 0u, 1u);

// ---------------- gumbel helpers ----------------
__device__ inline float bits_to_u(unsigned bits) {
  float f = __uint_as_float((bits >> 9) | 0x3f800000u) - 1.0f;
  f = f + 1e-10f;
  return fmaxf(1e-10f, f);
}
__device__ inline float u_to_g_exact(float u) {
  float l1 = (float)log((double)u);
  float l2 = (float)log((double)(-l1));
  return -l2;
}
__device__ inline float u_to_g_fast(float u) {
  float l1 = logf(u);
  float l2 = logf(-l1);
  return -l2;
}
__device__ inline unsigned ordf(float f) {
  unsigned u = __float_as_uint(f);
  return (u & 0x80000000u) ? ~u : (u | 0x80000000u);
}
__device__ inline float unordf(unsigned u) {
  return (u & 0x80000000u) ? __uint_as_float(u ^ 0x80000000u)
                           : __uint_as_float(~u);
}
__device__ inline unsigned long long packcand(float val, int p) {
  return ((unsigned long long)ordf(val) << 32) | (unsigned)(255 - p);
}
__device__ inline unsigned long long umax64(unsigned long long a,
                                            unsigned long long b) {
  return a > b ? a : b;
}
__device__ inline unsigned long long wave_max_ull(unsigned long long v) {
#pragma unroll
  for (int s = 32; s > 0; s >>= 1)
    v = umax64(v, (unsigned long long)__shfl_xor((unsigned long long)v, s, 64));
  return v;
}

__global__ __launch_bounds__(256) void gumbel_kernel(
    const float* __restrict__ voltage, const float* __restrict__ phase_func,
    const float* __restrict__ intensity_func, float2* __restrict__ PT) {
  const int q = blockIdx.x;
  const int p = threadIdx.x;
  const int wave = p >> 6, lane = p & 63;
  const unsigned idx = (unsigned)q * 256u + (unsigned)p;
  const float v = voltage[(size_t)q * 256 + p];
  TFOut r1 = tf2x32(KEY1.a, KEY1.b, 0u, idx);
  TFOut r2 = tf2x32(KEY2.a, KEY2.b, 0u, idx);
  const float u1 = bits_to_u(r1.a ^ r1.b);
  const float u2 = bits_to_u(r2.a ^ r2.b);
  const float c1a = (v + u_to_g_fast(u1)) * 0.1f;
  const float c2a = (v + u_to_g_fast(u2)) * 0.1f;

  __shared__ unsigned long long wred[2][4];
  __shared__ int wcnt[2][4];

  unsigned long long pk1 = wave_max_ull(packcand(c1a, p));
  unsigned long long pk2 = wave_max_ull(packcand(c2a, p));
  if (lane == 0) { wred[0][wave] = pk1; wred[1][wave] = pk2; }
  __syncthreads();
  unsigned long long b1 = umax64(umax64(wred[0][0], wred[0][1]),
                                 umax64(wred[0][2], wred[0][3]));
  unsigned long long b2 = umax64(umax64(wred[1][0], wred[1][1]),
                                 umax64(wred[1][2], wred[1][3]));
  const float eps = 1e-5f;
  const bool q1 = c1a >= unordf((unsigned)(b1 >> 32)) - eps;
  const bool q2 = c2a >= unordf((unsigned)(b2 >> 32)) - eps;
  unsigned long long bal1 = __ballot(q1);
  unsigned long long bal2 = __ballot(q2);
  if (lane == 0) { wcnt[0][wave] = __popcll(bal1); wcnt[1][wave] = __popcll(bal2); }
  __syncthreads();
  const int n1 = wcnt[0][0] + wcnt[0][1] + wcnt[0][2] + wcnt[0][3];
  const int n2 = wcnt[1][0] + wcnt[1][1] + wcnt[1][2] + wcnt[1][3];

  unsigned long long w1 = b1, w2 = b2;
  if (n1 > 1 || n2 > 1) {  // rare block-uniform exact path
    unsigned long long e1 = q1 ? packcand((v + u_to_g_exact(u1)) / 10.0f, p) : 0ull;
    unsigned long long e2 = q2 ? packcand((v + u_to_g_exact(u2)) / 10.0f, p) : 0ull;
    e1 = wave_max_ull(e1);
    e2 = wave_max_ull(e2);
    if (lane == 0) { wred[0][wave] = e1; wred[1][wave] = e2; }
    __syncthreads();
    w1 = umax64(umax64(wred[0][0], wred[0][1]), umax64(wred[0][2], wred[0][3]));
    w2 = umax64(umax64(wred[1][0], wred[1][1]), umax64(wred[1][2], wred[1][3]));
  }
  if (p == 0) {
    int i1 = 255 - (int)(w1 & 0xFFFFFFFFull);
    int i2 = 255 - (int)(w2 & 0xFFFFFFFFull);
    float phi = phase_func[i1];
    float amp = intensity_func[i2] * 6.0f;
    PT[q] = make_float2(amp * cosf(phi), amp * sinf(phi));
  }
}

// ---------------- tables ----------------
__global__ __launch_bounds__(256) void build_tw(float2* __restrict__ tw) {
  int m = threadIdx.x;
  if (m < S) {
    double ang = -2.0 * 3.1415926535897932384626433832795 * (double)m / (double)S;
    tw[m] = make_float2((float)cos(ang), (float)sin(ang));
  }
}

__device__ inline unsigned short bf16_rne(float x) {
  unsigned u = __float_as_uint(x);
  return (unsigned short)((u + 0x7FFFu + ((u >> 16) & 1u)) >> 16);
}
__device__ inline void split_bf16(float x, unsigned short& h, unsigned short& l) {
  h = bf16_rne(x);
  float hf = __uint_as_float(((unsigned)h) << 16);
  l = bf16_rne(x - hf);
}

// bf16 hi/lo planes of F and G (padded 224x224) + transposed h table
__global__ __launch_bounds__(256) void build_planes_ht(
    const float2* __restrict__ tw, const float* __restrict__ h_real,
    const float* __restrict__ h_imag, unsigned short* __restrict__ PL,
    float2* __restrict__ HT) {
  int idx = blockIdx.x * 256 + threadIdx.x;  // 196*256 = 50176 = PS exact
  int m = idx / KP, k = idx - (idx / KP) * KP;
  float fr = 0.f, fi = 0.f;
  if (m < S && k < S) {
    float2 t = tw[(m * k) % S];
    fr = t.x; fi = t.y;
  }
  unsigned short h, l;
  split_bf16(fr, h, l);           PL[0 * PS + idx] = h; PL[1 * PS + idx] = l;
  split_bf16(fi, h, l);           PL[2 * PS + idx] = h; PL[3 * PS + idx] = l;
  split_bf16(fr * 0.005f, h, l);  PL[4 * PS + idx] = h; PL[5 * PS + idx] = l;
  split_bf16(-fi * 0.005f, h, l); PL[6 * PS + idx] = h; PL[7 * PS + idx] = l;
  if (idx < SS) {  // HT[n][k] = h[k][n]
    int kk = idx / S, n = idx - (idx / S) * S;
    HT[n * S + kk] = make_float2(h_real[idx], h_imag[idx]);
  }
}

// ---------------- MFMA split-bf16 GEMM, 32x32 tiles ----------------
// out[m][(b,n)] = sum_k Op[m][k] * Bop[k][(b,n)], Op = F or G (bf16 planes).
// MODE 0: Bop = waves[b][k][n] (re/im planes)
// MODE 1: Bop = Sprev[b*200+n][k]
// MODE 2: Bop = Sprev[b*200+n][k] * h[k][n]  (via HT[n][k])
// Output stored Sout[(b*200+m)*200 + n]. FINAL: multiply by PT[n*200+m].
template <int MODE, bool FINAL>
__global__ __launch_bounds__(256) void gemm_mfma(
    const unsigned short* __restrict__ APL, const float* __restrict__ Wre,
    const float* __restrict__ Wim, const float2* __restrict__ Sprev,
    const float2* __restrict__ HT, const float2* __restrict__ PT,
    float2* __restrict__ Sout) {
  __shared__ short As[4][32][40];  // planes rh,rl,ih,il ; [m][k] k-contig
  __shared__ short Bs[4][32][40];  // planes ; [n][k] k-contig
  const int tid = threadIdx.x;
  const int wave = tid >> 6, lane = tid & 63, quad = lane >> 4, l15 = lane & 15;
  const int mb = blockIdx.x * 32;  // 0..192 (padded M=224)
  const int cb = blockIdx.y * 32;  // flat col base, N=3200
  const int mh = wave & 1, nh = wave >> 1;

  // A staging: plane, row, two k-groups {g*8, g*8+16}
  const int ap_ = tid >> 6;
  const int ar = (tid & 63) >> 1;
  const int ag = (tid & 1) * 8;
  const unsigned short* abase = APL + ap_ * PS + (mb + ar) * KP;

  // B staging: col (0..31), k-quad (0,4,..,28)
  const int bc = tid >> 3;
  const int bkq = (tid & 7) * 4;
  const int cB = cb + bc;
  const int bB = cB / S;
  const int nB = cB - bB * S;

  float4v accRR = {0.f, 0.f, 0.f, 0.f}, accII = {0.f, 0.f, 0.f, 0.f};
  float4v accRI = {0.f, 0.f, 0.f, 0.f}, accIR = {0.f, 0.f, 0.f, 0.f};

  for (int ch = 0; ch < 7; ++ch) {
    const int kc = ch * 32;
    short8 a0 = *(const short8*)(abase + kc + ag);
    short8 a1 = *(const short8*)(abase + kc + ag + 16);

    float re[4], im[4];
#pragma unroll
    for (int j = 0; j < 4; ++j) { re[j] = 0.f; im[j] = 0.f; }
    const int gk = kc + bkq;
    if (gk < S) {  // group of 4 entirely valid (S%4==0)
      if (MODE == 0) {
#pragma unroll
        for (int j = 0; j < 4; ++j) {
          re[j] = Wre[(long)bB * SS + (gk + j) * S + nB];
          im[j] = Wim[(long)bB * SS + (gk + j) * S + nB];
        }
      } else {
        const float2* bp = &Sprev[(long)(bB * S + nB) * S + gk];
#pragma unroll
        for (int j = 0; j < 4; ++j) { re[j] = bp[j].x; im[j] = bp[j].y; }
        if (MODE == 2) {
          const float2* hp = &HT[(long)nB * S + gk];
#pragma unroll
          for (int j = 0; j < 4; ++j) {
            float2 hv = hp[j];
            float tr = re[j] * hv.x - im[j] * hv.y;
            im[j] = re[j] * hv.y + im[j] * hv.x;
            re[j] = tr;
          }
        }
      }
    }
    short4v rh, rl, ih, il;
#pragma unroll
    for (int j = 0; j < 4; ++j) {
      unsigned short h_, l_;
      split_bf16(re[j], h_, l_); rh[j] = (short)h_; rl[j] = (short)l_;
      split_bf16(im[j], h_, l_); ih[j] = (short)h_; il[j] = (short)l_;
    }

    __syncthreads();  // previous chunk's frag reads complete
    *(short8*)&As[ap_][ar][ag] = a0;
    *(short8*)&As[ap_][ar][ag + 16] = a1;
    *(short4v*)&Bs[0][bc][bkq] = rh;
    *(short4v*)&Bs[1][bc][bkq] = rl;
    *(short4v*)&Bs[2][bc][bkq] = ih;
    *(short4v*)&Bs[3][bc][bkq] = il;
    __syncthreads();

    const int amr = mh * 16 + l15;
    const int bnr = nh * 16 + l15;
    short8 Arh = *(const short8*)&As[0][amr][quad * 8];
    short8 Arl = *(const short8*)&As[1][amr][quad * 8];
    short8 Aih = *(const short8*)&As[2][amr][quad * 8];
    short8 Ail = *(const short8*)&As[3][amr][quad * 8];
    short8 Brh = *(const short8*)&Bs[0][bnr][quad * 8];
    short8 Brl = *(const short8*)&Bs[1][bnr][quad * 8];
    short8 Bih = *(const short8*)&Bs[2][bnr][quad * 8];
    short8 Bil = *(const short8*)&Bs[3][bnr][quad * 8];

    accRR = __builtin_amdgcn_mfma_f32_16x16x32_bf16(Arh, Brh, accRR, 0, 0, 0);
    accRR = __builtin_amdgcn_mfma_f32_16x16x32_bf16(Arh, Brl, accRR, 0, 0, 0);
    accRR = __builtin_amdgcn_mfma_f32_16x16x32_bf16(Arl, Brh, accRR, 0, 0, 0);
    accII = __builtin_amdgcn_mfma_f32_16x16x32_bf16(Aih, Bih, accII, 0, 0, 0);
    accII = __builtin_amdgcn_mfma_f32_16x16x32_bf16(Aih, Bil, accII, 0, 0, 0);
    accII = __builtin_amdgcn_mfma_f32_16x16x32_bf16(Ail, Bih, accII, 0, 0, 0);
    accRI = __builtin_amdgcn_mfma_f32_16x16x32_bf16(Arh, Bih, accRI, 0, 0, 0);
    accRI = __builtin_amdgcn_mfma_f32_16x16x32_bf16(Arh, Bil, accRI, 0, 0, 0);
    accRI = __builtin_amdgcn_mfma_f32_16x16x32_bf16(Arl, Bih, accRI, 0, 0, 0);
    accIR = __builtin_amdgcn_mfma_f32_16x16x32_bf16(Aih, Brh, accIR, 0, 0, 0);
    accIR = __builtin_amdgcn_mfma_f32_16x16x32_bf16(Aih, Brl, accIR, 0, 0, 0);
    accIR = __builtin_amdgcn_mfma_f32_16x16x32_bf16(Ail, Brh, accIR, 0, 0, 0);
  }

  // epilogue: C/D layout col=l15, row=quad*4+r
  const int cg = cb + nh * 16 + l15;
  const int b = cg / S;
  const int n = cg - b * S;
#pragma unroll
  for (int r = 0; r < 4; ++r) {
    const int m = mb + mh * 16 + quad * 4 + r;
    if (m < S) {
      float Cr = accRR[r] - accII[r];
      float Ci = accRI[r] + accIR[r];
      if (FINAL) {
        float2 pt = PT[n * S + m];
        float tr = Cr * pt.x - Ci * pt.y;
        Ci = Cr * pt.y + Ci * pt.x;
        Cr = tr;
      }
      Sout[(long)(b * S + m) * S + n] = make_float2(Cr, Ci);
    }
  }
}

// ---------------- 10x pixel expansion ----------------
// S4[(b*200+j)*200 + i] = X_b[i][j] (phase applied). out (16,2000,2000,2).
__global__ __launch_bounds__(256) void expand_kernel(
    const float2* __restrict__ S4, float4v* __restrict__ out) {
  unsigned q = blockIdx.x * 256u + threadIdx.x;  // < 32,000,000 exact
  unsigned p0 = q * 2u;
  unsigned b = p0 / 4000000u;
  unsigned rem = p0 - b * 4000000u;
  unsigned r = rem / 2000u;
  unsigned c0 = rem - r * 2000u;
  unsigned i = r / 10u;
  unsigned dr = r - i * 10u;
  float4v o = {0.f, 0.f, 0.f, 0.f};
  if (dr - 1u <= 7u) {  // dr in [1,8]
    unsigned j = c0 / 10u;
    unsigned dc = c0 - j * 10u;  // even: 0,2,4,6,8
    float2 xv = S4[(b * 200u + j) * 200u + i];
    if (dc != 0u) { o.x = xv.x; o.y = xv.y; }
    if (dc != 8u) { o.z = xv.x; o.w = xv.y; }
  }
  __builtin_nontemporal_store(o, &out[q]);  // write-once stream, skip L2 alloc
}

// ---------------- launch ----------------
extern "C" void kernel_launch(void* const* d_in, const int* in_sizes, int n_in,
                              void* d_out, int out_size, void* d_ws, size_t ws_size,
                              hipStream_t stream) {
  const float* waves_real = (const float*)d_in[0];
  const float* waves_imag = (const float*)d_in[1];
  const float* h_real = (const float*)d_in[2];
  const float* h_imag = (const float*)d_in[3];
  const float* voltage = (const float*)d_in[4];
  const float* phase_func = (const float*)d_in[5];
  const float* intensity_func = (const float*)d_in[6];

  float2* TW = (float2*)d_ws;      // 256
  float2* HT = TW + 256;           // 40000
  float2* PT = HT + SS;            // 40000
  float2* S1 = PT + SS;            // 640000 each
  float2* S2 = S1 + SLICE;
  float2* S3 = S2 + SLICE;
  float2* S4 = S3 + SLICE;
  unsigned short* PL = (unsigned short*)(S4 + SLICE);  // 8 * 50176 bf16

  build_tw<<<1, 256, 0, stream>>>(TW);
  build_planes_ht<<<196, 256, 0, stream>>>(TW, h_real, h_imag, PL, HT);
  gumbel_kernel<<<40000, 256, 0, stream>>>(voltage, phase_func, intensity_func, PT);

  const unsigned short* FP = PL;           // F planes
  const unsigned short* GP = PL + 4 * PS;  // G planes
  dim3 g(7, 100);  // 700 blocks: ~2.7 blocks/CU
  // S1[b*200+m][n] = T1_b[m][n],  T1_b = F @ W_b
  gemm_mfma<0, false><<<g, 256, 0, stream>>>(FP, waves_real, waves_imag,
                                             nullptr, nullptr, nullptr, S1);
  // S2[b*200+m][n] = T2_b[n][m],  T2_b = T1_b @ F  (computed as F @ T1_b^T)
  gemm_mfma<1, false><<<g, 256, 0, stream>>>(FP, nullptr, nullptr, S1,
                                             nullptr, nullptr, S2);
  // S3[b*200+m][n] = T4_b[m][n],  T4_b = G @ (T2_b .* h)
  gemm_mfma<2, false><<<g, 256, 0, stream>>>(GP, nullptr, nullptr, S2,
                                             HT, nullptr, S3);
  // S4[b*200+m][n] = X_b[n][m]*PT, X_b = T4_b @ G  (computed as G @ T4_b^T)
  gemm_mfma<1, true><<<g, 256, 0, stream>>>(GP, nullptr, nullptr, S3,
                                            nullptr, PT, S4);

  expand_kernel<<<125000, 256, 0, stream>>>(S4, (float4v*)d_out);
}

// Round 11
// 632.868 us; speedup vs baseline: 1.3866x; 1.0039x over previous
//
#include <hip/hip_runtime.h>
#include <math.h>

constexpr int S = 200;
constexpr int SS = S * S;           // 40000
constexpr int SLICE = 640000;       // 200*3200 complex
constexpr int MP = 224;             // padded rows (7 tiles of 32)
constexpr int KP = 224;             // padded K (7 chunks of 32)
constexpr int PS = MP * KP;         // 50176 elements per A bf16 plane

typedef short short8 __attribute__((ext_vector_type(8)));
typedef short short4v __attribute__((ext_vector_type(4)));
typedef float float4v __attribute__((ext_vector_type(4)));

// ---------------- threefry2x32 (JAX-compatible, 20 rounds) ----------------
struct TFOut { unsigned a, b; };

__host__ __device__ constexpr TFOut tf2x32(unsigned k0, unsigned k1,
                                           unsigned x0, unsigned x1) {
  unsigned ks2 = k0 ^ k1 ^ 0x1BD11BDAu;
  unsigned ks[3] = {k0, k1, ks2};
  const int R0[4] = {13, 15, 26, 6};
  const int R1[4] = {17, 29, 16, 24};
  x0 += ks[0]; x1 += ks[1];
  for (int i = 0; i < 5; ++i) {
    const int* R = (i & 1) ? R1 : R0;
    for (int j = 0; j < 4; ++j) {
      x0 += x1;
      x1 = (x1 << R[j]) | (x1 >> (32 - R[j]));
      x1 ^= x0;
    }
    x0 += ks[(i + 1) % 3];
    x1 += ks[(i + 2) % 3] + (unsigned)(i + 1);
  }
  return {x0, x1};
}

constexpr TFOut KEY1 = tf2x32(0u, 42u, 0u, 0u);
constexpr TFOut KEY2 = tf2x32(0u, 42u, 0u, 1u);

// ---------------- gumbel helpers ----------------
__device__ inline float bits_to_u(unsigned bits) {
  float f = __uint_as_float((bits >> 9) | 0x3f800000u) - 1.0f;
  f = f + 1e-10f;
  return fmaxf(1e-10f, f);
}
__device__ inline float u_to_g_exact(float u) {
  float l1 = (float)log((double)u);
  float l2 = (float)log((double)(-l1));
  return -l2;
}
__device__ inline float u_to_g_fast(float u) {
  float l1 = logf(u);
  float l2 = logf(-l1);
  return -l2;
}
__device__ inline unsigned ordf(float f) {
  unsigned u = __float_as_uint(f);
  return (u & 0x80000000u) ? ~u : (u | 0x80000000u);
}
__device__ inline float unordf(unsigned u) {
  return (u & 0x80000000u) ? __uint_as_float(u ^ 0x80000000u)
                           : __uint_as_float(~u);
}
__device__ inline unsigned long long packcand(float val, int p) {
  return ((unsigned long long)ordf(val) << 32) | (unsigned)(255 - p);
}
__device__ inline unsigned long long umax64(unsigned long long a,
                                            unsigned long long b) {
  return a > b ? a : b;
}
__device__ inline unsigned long long wave_max_ull(unsigned long long v) {
#pragma unroll
  for (int s = 32; s > 0; s >>= 1)
    v = umax64(v, (unsigned long long)__shfl_xor((unsigned long long)v, s, 64));
  return v;
}

__global__ __launch_bounds__(256) void gumbel_kernel(
    const float* __restrict__ voltage, const float* __restrict__ phase_func,
    const float* __restrict__ intensity_func, float2* __restrict__ PT) {
  const int q = blockIdx.x;
  const int p = threadIdx.x;
  const int wave = p >> 6, lane = p & 63;
  const unsigned idx = (unsigned)q * 256u + (unsigned)p;
  const float v = voltage[(size_t)q * 256 + p];
  TFOut r1 = tf2x32(KEY1.a, KEY1.b, 0u, idx);
  TFOut r2 = tf2x32(KEY2.a, KEY2.b, 0u, idx);
  const float u1 = bits_to_u(r1.a ^ r1.b);
  const float u2 = bits_to_u(r2.a ^ r2.b);
  const float c1a = (v + u_to_g_fast(u1)) * 0.1f;
  const float c2a = (v + u_to_g_fast(u2)) * 0.1f;

  __shared__ unsigned long long wred[2][4];
  __shared__ int wcnt[2][4];

  unsigned long long pk1 = wave_max_ull(packcand(c1a, p));
  unsigned long long pk2 = wave_max_ull(packcand(c2a, p));
  if (lane == 0) { wred[0][wave] = pk1; wred[1][wave] = pk2; }
  __syncthreads();
  unsigned long long b1 = umax64(umax64(wred[0][0], wred[0][1]),
                                 umax64(wred[0][2], wred[0][3]));
  unsigned long long b2 = umax64(umax64(wred[1][0], wred[1][1]),
                                 umax64(wred[1][2], wred[1][3]));
  const float eps = 1e-5f;
  const bool q1 = c1a >= unordf((unsigned)(b1 >> 32)) - eps;
  const bool q2 = c2a >= unordf((unsigned)(b2 >> 32)) - eps;
  unsigned long long bal1 = __ballot(q1);
  unsigned long long bal2 = __ballot(q2);
  if (lane == 0) { wcnt[0][wave] = __popcll(bal1); wcnt[1][wave] = __popcll(bal2); }
  __syncthreads();
  const int n1 = wcnt[0][0] + wcnt[0][1] + wcnt[0][2] + wcnt[0][3];
  const int n2 = wcnt[1][0] + wcnt[1][1] + wcnt[1][2] + wcnt[1][3];

  unsigned long long w1 = b1, w2 = b2;
  if (n1 > 1 || n2 > 1) {  // rare block-uniform exact path
    unsigned long long e1 = q1 ? packcand((v + u_to_g_exact(u1)) / 10.0f, p) : 0ull;
    unsigned long long e2 = q2 ? packcand((v + u_to_g_exact(u2)) / 10.0f, p) : 0ull;
    e1 = wave_max_ull(e1);
    e2 = wave_max_ull(e2);
    if (lane == 0) { wred[0][wave] = e1; wred[1][wave] = e2; }
    __syncthreads();
    w1 = umax64(umax64(wred[0][0], wred[0][1]), umax64(wred[0][2], wred[0][3]));
    w2 = umax64(umax64(wred[1][0], wred[1][1]), umax64(wred[1][2], wred[1][3]));
  }
  if (p == 0) {
    int i1 = 255 - (int)(w1 & 0xFFFFFFFFull);
    int i2 = 255 - (int)(w2 & 0xFFFFFFFFull);
    float phi = phase_func[i1];
    float amp = intensity_func[i2] * 6.0f;
    PT[q] = make_float2(amp * cosf(phi), amp * sinf(phi));
  }
}

// ---------------- tables ----------------
__device__ inline unsigned short bf16_rne(float x) {
  unsigned u = __float_as_uint(x);
  return (unsigned short)((u + 0x7FFFu + ((u >> 16) & 1u)) >> 16);
}
__device__ inline void split_bf16(float x, unsigned short& h, unsigned short& l) {
  h = bf16_rne(x);
  float hf = __uint_as_float(((unsigned)h) << 16);
  l = bf16_rne(x - hf);
}

// bf16 hi/lo planes of F and G (padded 224x224) + transposed h table.
// Twiddles built per-block in LDS (fused, no separate launch).
__global__ __launch_bounds__(256) void build_planes_ht(
    const float* __restrict__ h_real, const float* __restrict__ h_imag,
    unsigned short* __restrict__ PL, float2* __restrict__ HT) {
  __shared__ float2 tw[S];
  const int t = threadIdx.x;
  if (t < S) {
    double ang = -2.0 * 3.1415926535897932384626433832795 * (double)t / (double)S;
    tw[t] = make_float2((float)cos(ang), (float)sin(ang));
  }
  __syncthreads();
  int idx = blockIdx.x * 256 + t;  // 196*256 = 50176 = PS exact
  int m = idx / KP, k = idx - (idx / KP) * KP;
  float fr = 0.f, fi = 0.f;
  if (m < S && k < S) {
    float2 tv = tw[(m * k) % S];
    fr = tv.x; fi = tv.y;
  }
  unsigned short h, l;
  split_bf16(fr, h, l);           PL[0 * PS + idx] = h; PL[1 * PS + idx] = l;
  split_bf16(fi, h, l);           PL[2 * PS + idx] = h; PL[3 * PS + idx] = l;
  split_bf16(fr * 0.005f, h, l);  PL[4 * PS + idx] = h; PL[5 * PS + idx] = l;
  split_bf16(-fi * 0.005f, h, l); PL[6 * PS + idx] = h; PL[7 * PS + idx] = l;
  if (idx < SS) {  // HT[n][k] = h[k][n]
    int kk = idx / S, n = idx - (idx / S) * S;
    HT[n * S + kk] = make_float2(h_real[idx], h_imag[idx]);
  }
}

// ---------------- MFMA split-bf16 GEMM, 32x32 tiles ----------------
// out[m][(b,n)] = sum_k Op[m][k] * Bop[k][(b,n)], Op = F or G (A planes).
// MODE 0: Bop = waves[b][k][n] (re/im planes)
// MODE 1: Bop = Sprev[b*200+n][k]
// MODE 2: Bop = Sprev[b*200+n][k] * h[k][n]  (via HT[n][k])
// Output stored Sout[(b*200+m)*200 + n]. FINAL: multiply by PT[n*200+m].
template <int MODE, bool FINAL>
__global__ __launch_bounds__(256) void gemm_mfma(
    const unsigned short* __restrict__ APL, const float* __restrict__ Wre,
    const float* __restrict__ Wim, const float2* __restrict__ Sprev,
    const float2* __restrict__ HT, const float2* __restrict__ PT,
    float2* __restrict__ Sout) {
  __shared__ short As[4][32][40];  // planes rh,rl,ih,il ; [m][k] k-contig
  __shared__ short Bs[4][32][40];  // planes ; [n][k] k-contig
  const int tid = threadIdx.x;
  const int wave = tid >> 6, lane = tid & 63, quad = lane >> 4, l15 = lane & 15;
  const int mb = blockIdx.x * 32;  // 0..192 (padded M=224)
  const int cb = blockIdx.y * 32;  // flat col base, N=3200
  const int mh = wave & 1, nh = wave >> 1;

  // A staging: plane, row, two k-groups {g*8, g*8+16}
  const int ap_ = tid >> 6;
  const int ar = (tid & 63) >> 1;
  const int ag = (tid & 1) * 8;
  const unsigned short* abase = APL + ap_ * PS + (mb + ar) * KP;

  // B staging: col (0..31), k-quad (0,4,..,28)
  const int bc = tid >> 3;
  const int bkq = (tid & 7) * 4;
  const int cB = cb + bc;
  const int bB0 = cB / S;
  const int nB0 = cB - bB0 * S;

  float4v accRR = {0.f, 0.f, 0.f, 0.f}, accII = {0.f, 0.f, 0.f, 0.f};
  float4v accRI = {0.f, 0.f, 0.f, 0.f}, accIR = {0.f, 0.f, 0.f, 0.f};

  for (int ch = 0; ch < 7; ++ch) {
    const int kc = ch * 32;
    short8 a0 = *(const short8*)(abase + kc + ag);
    short8 a1 = *(const short8*)(abase + kc + ag + 16);

    float re[4], im[4];
#pragma unroll
    for (int j = 0; j < 4; ++j) { re[j] = 0.f; im[j] = 0.f; }
    const int gk = kc + bkq;
    if (gk < S) {  // group of 4 entirely valid (S%4==0)
      if (MODE == 0) {
#pragma unroll
        for (int j = 0; j < 4; ++j) {
          re[j] = Wre[(long)bB0 * SS + (gk + j) * S + nB0];
          im[j] = Wim[(long)bB0 * SS + (gk + j) * S + nB0];
        }
      } else {
        const float2* bp = &Sprev[(long)(bB0 * S + nB0) * S + gk];
#pragma unroll
        for (int j = 0; j < 4; ++j) { re[j] = bp[j].x; im[j] = bp[j].y; }
        if (MODE == 2) {
          const float2* hp = &HT[(long)nB0 * S + gk];
#pragma unroll
          for (int j = 0; j < 4; ++j) {
            float2 hv = hp[j];
            float tr = re[j] * hv.x - im[j] * hv.y;
            im[j] = re[j] * hv.y + im[j] * hv.x;
            re[j] = tr;
          }
        }
      }
    }
    short4v rh, rl, ih, il;
#pragma unroll
    for (int j = 0; j < 4; ++j) {
      unsigned short h_, l_;
      split_bf16(re[j], h_, l_); rh[j] = (short)h_; rl[j] = (short)l_;
      split_bf16(im[j], h_, l_); ih[j] = (short)h_; il[j] = (short)l_;
    }

    __syncthreads();  // previous chunk's frag reads complete
    *(short8*)&As[ap_][ar][ag] = a0;
    *(short8*)&As[ap_][ar][ag + 16] = a1;
    *(short4v*)&Bs[0][bc][bkq] = rh;
    *(short4v*)&Bs[1][bc][bkq] = rl;
    *(short4v*)&Bs[2][bc][bkq] = ih;
    *(short4v*)&Bs[3][bc][bkq] = il;
    __syncthreads();

    const int amr = mh * 16 + l15;
    const int bnr = nh * 16 + l15;
    short8 Arh = *(const short8*)&As[0][amr][quad * 8];
    short8 Arl = *(const short8*)&As[1][amr][quad * 8];
    short8 Aih = *(const short8*)&As[2][amr][quad * 8];
    short8 Ail = *(const short8*)&As[3][amr][quad * 8];
    short8 Brh = *(const short8*)&Bs[0][bnr][quad * 8];
    short8 Brl = *(const short8*)&Bs[1][bnr][quad * 8];
    short8 Bih = *(const short8*)&Bs[2][bnr][quad * 8];
    short8 Bil = *(const short8*)&Bs[3][bnr][quad * 8];

    accRR = __builtin_amdgcn_mfma_f32_16x16x32_bf16(Arh, Brh, accRR, 0, 0, 0);
    accRR = __builtin_amdgcn_mfma_f32_16x16x32_bf16(Arh, Brl, accRR, 0, 0, 0);
    accRR = __builtin_amdgcn_mfma_f32_16x16x32_bf16(Arl, Brh, accRR, 0, 0, 0);
    accII = __builtin_amdgcn_mfma_f32_16x16x32_bf16(Aih, Bih, accII, 0, 0, 0);
    accII = __builtin_amdgcn_mfma_f32_16x16x32_bf16(Aih, Bil, accII, 0, 0, 0);
    accII = __builtin_amdgcn_mfma_f32_16x16x32_bf16(Ail, Bih, accII, 0, 0, 0);
    accRI = __builtin_amdgcn_mfma_f32_16x16x32_bf16(Arh, Bih, accRI, 0, 0, 0);
    accRI = __builtin_amdgcn_mfma_f32_16x16x32_bf16(Arh, Bil, accRI, 0, 0, 0);
    accRI = __builtin_amdgcn_mfma_f32_16x16x32_bf16(Arl, Bih, accRI, 0, 0, 0);
    accIR = __builtin_amdgcn_mfma_f32_16x16x32_bf16(Aih, Brh, accIR, 0, 0, 0);
    accIR = __builtin_amdgcn_mfma_f32_16x16x32_bf16(Aih, Brl, accIR, 0, 0, 0);
    accIR = __builtin_amdgcn_mfma_f32_16x16x32_bf16(Ail, Brh, accIR, 0, 0, 0);
  }

  // epilogue: C/D layout col=l15, row=quad*4+r
  const int cg = cb + nh * 16 + l15;
  const int b = cg / S;
  const int n = cg - b * S;
#pragma unroll
  for (int r = 0; r < 4; ++r) {
    const int m = mb + mh * 16 + quad * 4 + r;
    if (m < S) {
      float Cr = accRR[r] - accII[r];
      float Ci = accRI[r] + accIR[r];
      if (FINAL) {
        float2 pt = PT[n * S + m];
        float tr = Cr * pt.x - Ci * pt.y;
        Ci = Cr * pt.y + Ci * pt.x;
        Cr = tr;
      }
      Sout[(long)(b * S + m) * S + n] = make_float2(Cr, Ci);
    }
  }
}

// ---------------- 10x pixel expansion ----------------
// S4[(b*200+j)*200 + i] = X_b[i][j] (phase applied). out (16,2000,2000,2).
__global__ __launch_bounds__(256) void expand_kernel(
    const float2* __restrict__ S4, float4v* __restrict__ out) {
  unsigned q = blockIdx.x * 256u + threadIdx.x;  // < 32,000,000 exact
  unsigned p0 = q * 2u;
  unsigned b = p0 / 4000000u;
  unsigned rem = p0 - b * 4000000u;
  unsigned r = rem / 2000u;
  unsigned c0 = rem - r * 2000u;
  unsigned i = r / 10u;
  unsigned dr = r - i * 10u;
  float4v o = {0.f, 0.f, 0.f, 0.f};
  if (dr - 1u <= 7u) {  // dr in [1,8]
    unsigned j = c0 / 10u;
    unsigned dc = c0 - j * 10u;  // even: 0,2,4,6,8
    float2 xv = S4[(b * 200u + j) * 200u + i];
    if (dc != 0u) { o.x = xv.x; o.y = xv.y; }
    if (dc != 8u) { o.z = xv.x; o.w = xv.y; }
  }
  __builtin_nontemporal_store(o, &out[q]);  // write-once stream, skip L2 alloc
}

// ---------------- launch ----------------
extern "C" void kernel_launch(void* const* d_in, const int* in_sizes, int n_in,
                              void* d_out, int out_size, void* d_ws, size_t ws_size,
                              hipStream_t stream) {
  const float* waves_real = (const float*)d_in[0];
  const float* waves_imag = (const float*)d_in[1];
  const float* h_real = (const float*)d_in[2];
  const float* h_imag = (const float*)d_in[3];
  const float* voltage = (const float*)d_in[4];
  const float* phase_func = (const float*)d_in[5];
  const float* intensity_func = (const float*)d_in[6];

  float2* HT = (float2*)d_ws;      // 40000
  float2* PT = HT + SS;            // 40000
  float2* S1 = PT + SS;            // 640000 each
  float2* S2 = S1 + SLICE;
  float2* S3 = S2 + SLICE;
  float2* S4 = S3 + SLICE;
  unsigned short* PL = (unsigned short*)(S4 + SLICE);  // 8 * 50176 bf16

  build_planes_ht<<<196, 256, 0, stream>>>(h_real, h_imag, PL, HT);
  gumbel_kernel<<<40000, 256, 0, stream>>>(voltage, phase_func, intensity_func, PT);

  const unsigned short* FP = PL;           // F planes
  const unsigned short* GP = PL + 4 * PS;  // G planes
  dim3 g(7, 100);  // 700 blocks: ~2.7 blocks/CU
  // S1[b*200+m][n] = T1_b[m][n],  T1_b = F @ W_b
  gemm_mfma<0, false><<<g, 256, 0, stream>>>(FP, waves_real, waves_imag,
                                             nullptr, nullptr, nullptr, S1);
  // S2[b*200+m][n] = T2_b[n][m],  T2_b = T1_b @ F  (computed as F @ T1_b^T)
  gemm_mfma<1, false><<<g, 256, 0, stream>>>(FP, nullptr, nullptr, S1,
                                             nullptr, nullptr, S2);
  // S3[b*200+m][n] = T4_b[m][n],  T4_b = G @ (T2_b .* h)
  gemm_mfma<2, false><<<g, 256, 0, stream>>>(GP, nullptr, nullptr, S2,
                                             HT, nullptr, S3);
  // S4[b*200+m][n] = X_b[n][m]*PT, X_b = T4_b @ G  (computed as G @ T4_b^T)
  gemm_mfma<1, true><<<g, 256, 0, stream>>>(GP, nullptr, nullptr, S3,
                                            nullptr, PT, S4);

  expand_kernel<<<125000, 256, 0, stream>>>(S4, (float4v*)d_out);
}